// Round 5
// baseline (580.452 us; speedup 1.0000x reference)
//
#include <hip/hip_runtime.h>
#include <stdint.h>

// PMF: out[p] = relu(dot(U[user_ids[p]], V[item_ids[p]])), D=64.
// Round 5: fine-grained bucket sort by uid>>7 (8192 buckets, 128-row = 32KB
// windows) so the user-table gather stream is nearly address-sequential ->
// DRAM row-buffer locality lifts effective HBM BW (~2.8 -> ~5 TB/s theory).
// Pipeline: memset(hist) -> hist(global atomics) -> scan -> scatter(packed
// uint64 tuples) -> dot with XCD-contiguous swizzle, scattered out[pos].

constexpr int HIDDEN = 64;
constexpr int K      = 4;      // pairs per 16-lane group in dot kernel
constexpr int NB     = 8192;   // buckets
constexpr int BSHIFT = 7;      // bucket = uid >> 7  (max uid 999,999 -> 7812)

__device__ __forceinline__ float dot16(const float4& a, const float4& b) {
    return a.x * b.x + a.y * b.y + a.z * b.z + a.w * b.w;
}

__device__ __forceinline__ uint64_t pack_pair(int uid, int iid, int pos) {
    // uid: 20b, iid: 17b, pos: 21b
    return ((uint64_t)uid << 38) | ((uint64_t)iid << 21) | (uint64_t)pos;
}

__global__ __launch_bounds__(256) void hist_kernel(
    const int* __restrict__ user_ids, int* __restrict__ ghist, int n)
{
    const int stride = gridDim.x * blockDim.x;
    for (int p = blockIdx.x * blockDim.x + threadIdx.x; p < n; p += stride)
        atomicAdd(&ghist[user_ids[p] >> BSHIFT], 1);  // ~244 adds/address, parallel across 8192
}

__global__ __launch_bounds__(1024) void scan_kernel(
    const int* __restrict__ ghist, int* __restrict__ cursor)
{
    // 8192 values, 1024 threads x 8 values each: serial prefix + block scan.
    __shared__ int part[1024];
    const int t = threadIdx.x;
    int v[8];
    int4 h0 = reinterpret_cast<const int4*>(ghist)[t * 2];
    int4 h1 = reinterpret_cast<const int4*>(ghist)[t * 2 + 1];
    v[0] = h0.x; v[1] = h0.y; v[2] = h0.z; v[3] = h0.w;
    v[4] = h1.x; v[5] = h1.y; v[6] = h1.z; v[7] = h1.w;
    int sum = 0;
    #pragma unroll
    for (int i = 0; i < 8; ++i) { int x = v[i]; v[i] = sum; sum += x; }  // exclusive within chunk
    part[t] = sum;
    __syncthreads();
    #pragma unroll
    for (int d = 1; d < 1024; d <<= 1) {
        int x = (t >= d) ? part[t - d] : 0;
        __syncthreads();
        part[t] += x;
        __syncthreads();
    }
    const int base = part[t] - sum;  // exclusive prefix of this thread's chunk
    int4 o0 = { v[0] + base, v[1] + base, v[2] + base, v[3] + base };
    int4 o1 = { v[4] + base, v[5] + base, v[6] + base, v[7] + base };
    reinterpret_cast<int4*>(cursor)[t * 2]     = o0;
    reinterpret_cast<int4*>(cursor)[t * 2 + 1] = o1;
}

__global__ __launch_bounds__(256) void scatter_kernel(
    const int* __restrict__ user_ids, const int* __restrict__ item_ids,
    int* __restrict__ cursor, uint64_t* __restrict__ sorted, int n)
{
    const int stride = gridDim.x * blockDim.x;
    for (int p = blockIdx.x * blockDim.x + threadIdx.x; p < n; p += stride) {
        int u = user_ids[p];
        int q = atomicAdd(&cursor[u >> BSHIFT], 1);
        sorted[q] = pack_pair(u, item_ids[p], p);
    }
}

__global__ __launch_bounds__(256) void pmf_dot_sorted(
    const float* __restrict__ user_emb, const float* __restrict__ item_emb,
    const uint64_t* __restrict__ sorted, float* __restrict__ out,
    int n, int chunk)
{
    // XCD swizzle: HW assigns block b to XCD b%8; give XCD k a contiguous
    // q-range so a bucket's duplicate-user gathers hit the same XCD's L2.
    const int b2     = (blockIdx.x & 7) * chunk + (blockIdx.x >> 3);
    const int group  = b2 * 16 + (threadIdx.x >> 4);
    const int lane16 = threadIdx.x & 15;
    const int q0     = group * K;

    if (q0 + K <= n) {
        const ulonglong2 v01 = *reinterpret_cast<const ulonglong2*>(sorted + q0);
        const ulonglong2 v23 = *reinterpret_cast<const ulonglong2*>(sorted + q0 + 2);
        const uint64_t v0 = v01.x, v1 = v01.y, v2 = v23.x, v3 = v23.y;

        const int u0 = (int)(v0 >> 38), i0 = (int)((v0 >> 21) & 0x1FFFF), p0 = (int)(v0 & 0x1FFFFF);
        const int u1 = (int)(v1 >> 38), i1 = (int)((v1 >> 21) & 0x1FFFF), p1 = (int)(v1 & 0x1FFFFF);
        const int u2 = (int)(v2 >> 38), i2 = (int)((v2 >> 21) & 0x1FFFF), p2 = (int)(v2 & 0x1FFFFF);
        const int u3 = (int)(v3 >> 38), i3 = (int)((v3 >> 21) & 0x1FFFF), p3 = (int)(v3 & 0x1FFFFF);

        const float4 a0 = *(reinterpret_cast<const float4*>(user_emb + (size_t)u0 * HIDDEN) + lane16);
        const float4 a1 = *(reinterpret_cast<const float4*>(user_emb + (size_t)u1 * HIDDEN) + lane16);
        const float4 a2 = *(reinterpret_cast<const float4*>(user_emb + (size_t)u2 * HIDDEN) + lane16);
        const float4 a3 = *(reinterpret_cast<const float4*>(user_emb + (size_t)u3 * HIDDEN) + lane16);
        const float4 b0 = *(reinterpret_cast<const float4*>(item_emb + (size_t)i0 * HIDDEN) + lane16);
        const float4 b1 = *(reinterpret_cast<const float4*>(item_emb + (size_t)i1 * HIDDEN) + lane16);
        const float4 b2v = *(reinterpret_cast<const float4*>(item_emb + (size_t)i2 * HIDDEN) + lane16);
        const float4 b3 = *(reinterpret_cast<const float4*>(item_emb + (size_t)i3 * HIDDEN) + lane16);

        float d0 = dot16(a0, b0);
        float d1 = dot16(a1, b1);
        float d2 = dot16(a2, b2v);
        float d3 = dot16(a3, b3);

        #pragma unroll
        for (int s = 1; s < 16; s <<= 1) {
            d0 += __shfl_xor(d0, s, 16);
            d1 += __shfl_xor(d1, s, 16);
            d2 += __shfl_xor(d2, s, 16);
            d3 += __shfl_xor(d3, s, 16);
        }

        if (lane16 == 0) {
            out[p0] = d0 > 0.0f ? d0 : 0.0f;
            out[p1] = d1 > 0.0f ? d1 : 0.0f;
            out[p2] = d2 > 0.0f ? d2 : 0.0f;
            out[p3] = d3 > 0.0f ? d3 : 0.0f;
        }
    } else if (q0 < n) {
        for (int q = q0; q < n; ++q) {
            const uint64_t v = sorted[q];
            const int u = (int)(v >> 38), i = (int)((v >> 21) & 0x1FFFF), p = (int)(v & 0x1FFFFF);
            const float4 a = *(reinterpret_cast<const float4*>(user_emb + (size_t)u * HIDDEN) + lane16);
            const float4 b = *(reinterpret_cast<const float4*>(item_emb + (size_t)i * HIDDEN) + lane16);
            float d = dot16(a, b);
            #pragma unroll
            for (int s = 1; s < 16; s <<= 1) d += __shfl_xor(d, s, 16);
            if (lane16 == 0) out[p] = d > 0.0f ? d : 0.0f;
        }
    }
}

// Direct fallback (round-2 kernel) if ws too small.
__global__ __launch_bounds__(256) void pmf_dot_direct(
    const float* __restrict__ user_emb, const float* __restrict__ item_emb,
    const int* __restrict__ user_ids, const int* __restrict__ item_ids,
    float* __restrict__ out, int n)
{
    const int group  = (blockIdx.x * blockDim.x + threadIdx.x) >> 4;
    const int lane16 = threadIdx.x & 15;
    const int p0     = group * K;
    if (p0 + K <= n) {
        const int4 u4 = *reinterpret_cast<const int4*>(user_ids + p0);
        const int4 i4 = *reinterpret_cast<const int4*>(item_ids + p0);
        const float4 a0 = *(reinterpret_cast<const float4*>(user_emb + (size_t)u4.x * HIDDEN) + lane16);
        const float4 a1 = *(reinterpret_cast<const float4*>(user_emb + (size_t)u4.y * HIDDEN) + lane16);
        const float4 a2 = *(reinterpret_cast<const float4*>(user_emb + (size_t)u4.z * HIDDEN) + lane16);
        const float4 a3 = *(reinterpret_cast<const float4*>(user_emb + (size_t)u4.w * HIDDEN) + lane16);
        const float4 b0 = *(reinterpret_cast<const float4*>(item_emb + (size_t)i4.x * HIDDEN) + lane16);
        const float4 b1 = *(reinterpret_cast<const float4*>(item_emb + (size_t)i4.y * HIDDEN) + lane16);
        const float4 b2 = *(reinterpret_cast<const float4*>(item_emb + (size_t)i4.z * HIDDEN) + lane16);
        const float4 b3 = *(reinterpret_cast<const float4*>(item_emb + (size_t)i4.w * HIDDEN) + lane16);
        float d0 = dot16(a0, b0), d1 = dot16(a1, b1), d2 = dot16(a2, b2), d3 = dot16(a3, b3);
        #pragma unroll
        for (int s = 1; s < 16; s <<= 1) {
            d0 += __shfl_xor(d0, s, 16);
            d1 += __shfl_xor(d1, s, 16);
            d2 += __shfl_xor(d2, s, 16);
            d3 += __shfl_xor(d3, s, 16);
        }
        if (lane16 == 0) {
            float4 r = { d0 > 0.0f ? d0 : 0.0f, d1 > 0.0f ? d1 : 0.0f,
                         d2 > 0.0f ? d2 : 0.0f, d3 > 0.0f ? d3 : 0.0f };
            *reinterpret_cast<float4*>(out + p0) = r;
        }
    } else if (p0 < n) {
        for (int p = p0; p < n; ++p) {
            const int uid = user_ids[p];
            const int iid = item_ids[p];
            const float4 a = *(reinterpret_cast<const float4*>(user_emb + (size_t)uid * HIDDEN) + lane16);
            const float4 b = *(reinterpret_cast<const float4*>(item_emb + (size_t)iid * HIDDEN) + lane16);
            float d = dot16(a, b);
            #pragma unroll
            for (int s = 1; s < 16; s <<= 1) d += __shfl_xor(d, s, 16);
            if (lane16 == 0) out[p] = d > 0.0f ? d : 0.0f;
        }
    }
}

extern "C" void kernel_launch(void* const* d_in, const int* in_sizes, int n_in,
                              void* d_out, int out_size, void* d_ws, size_t ws_size,
                              hipStream_t stream) {
    const float* user_emb = (const float*)d_in[0];
    const float* item_emb = (const float*)d_in[1];
    const int*   user_ids = (const int*)d_in[2];
    const int*   item_ids = (const int*)d_in[3];
    float* out = (float*)d_out;

    const int n = in_sizes[2];  // 2,000,000

    // ws layout: ghist[NB] | cursor[NB] | sorted[n] (8B each)
    const size_t sortedOff = (size_t)2 * NB * 4;       // 64 KiB
    const size_t need      = sortedOff + (size_t)n * 8;

    const int threads = 256;
    const int pairs_per_dot_block = (threads / 16) * K;  // 64
    int dot_blocks = (n + pairs_per_dot_block - 1) / pairs_per_dot_block;

    if (ws_size >= need) {
        char* ws = (char*)d_ws;
        int*      ghist  = (int*)ws;
        int*      cursor = (int*)(ws + NB * 4);
        uint64_t* sorted = (uint64_t*)(ws + sortedOff);

        hipMemsetAsync(ghist, 0, NB * 4, stream);

        const int lin_blocks = 2048;  // grid-stride, ~8 waves/CU of work
        hist_kernel<<<lin_blocks, threads, 0, stream>>>(user_ids, ghist, n);
        scan_kernel<<<1, 1024, 0, stream>>>(ghist, cursor);
        scatter_kernel<<<lin_blocks, threads, 0, stream>>>(
            user_ids, item_ids, cursor, sorted, n);

        const int blocks8 = ((dot_blocks + 7) / 8) * 8;
        const int chunk   = blocks8 / 8;
        pmf_dot_sorted<<<blocks8, threads, 0, stream>>>(
            user_emb, item_emb, sorted, out, n, chunk);
    } else {
        pmf_dot_direct<<<dot_blocks, threads, 0, stream>>>(
            user_emb, item_emb, user_ids, item_ids, out, n);
    }
}